// Round 4
// baseline (156.582 us; speedup 1.0000x reference)
//
#include <hip/hip_runtime.h>

typedef _Float16 half_t;
typedef half_t f16x8 __attribute__((ext_vector_type(8)));
typedef float f32x4 __attribute__((ext_vector_type(4)));
typedef unsigned int u32x2 __attribute__((ext_vector_type(2)));

#define LOG2E 1.44269504088896340736f

// Problem dims (fixed)
#define NROWS 65536
#define DIN   64
#define NCTRS 1024
#define DOUT  256

// Workspace layout (bytes). ONE FRAGMENT = 64 lanes x 16 B = 1024 B.
#define CSWZ_OFF 0
#define CSWZ_BYTES (128 * 1024)
#define VSWZ_OFF (CSWZ_OFF + CSWZ_BYTES)            // 131072
#define VSWZ_BYTES (512 * 1024)
#define CSQ_OFF  (VSWZ_OFF + VSWZ_BYTES)            // 655360; end 659456

#define CT_STRIDE 68

// defer-max threshold in log2 units: p <= 2^8 = 256, safely inside f16 range
#define RESCALE_THR 8.0f

// ---------------------------------------------------------------------------
// Precompute, 256 blocks: c = bid & 31, part = bid >> 5.
// Each block converts a 32x32 slice of V for chunk c (douts part*32..+31) into
// 2 Vswz frags. part==0 blocks additionally do Cswz + csq for chunk c.
// Fragment layout (A/B symmetric): lane holds [idx=lane&15][k=8*(lane>>4)+j].
// ---------------------------------------------------------------------------
__global__ __launch_bounds__(256) void precompute_kernel(
    const float* __restrict__ ctrs, const float* __restrict__ values,
    const float* __restrict__ s, char* __restrict__ ws) {
  half_t* Cswz = (half_t*)(ws + CSWZ_OFF);
  half_t* Vswz = (half_t*)(ws + VSWZ_OFF);
  float* csq2 = (float*)(ws + CSQ_OFF);

  __shared__ half_t Vt[32 * 36];         // 32 x 32 (+4 pad)
  __shared__ half_t Ct[32 * CT_STRIDE];  // 32 x 64 (padded)

  const int bid = blockIdx.x, tid = threadIdx.x;
  const int c = bid & 31, part = bid >> 5;
  const int w = tid >> 6, l = tid & 63, l4 = l >> 4, lm = l & 15;

  {  // V subtile: rows c*32..+31, douts part*32..+31 -> 256 float4 (1/thread)
    int r = tid >> 3, f4 = tid & 7;
    float4 v = ((const float4*)values)[(size_t)(c * 32 + r) * 64 + part * 8 + f4];
    half_t* d = Vt + r * 36 + f4 * 4;
    d[0] = (half_t)v.x; d[1] = (half_t)v.y;
    d[2] = (half_t)v.z; d[3] = (half_t)v.w;
  }
  if (part == 0) {
    // C tile: 32x64 floats = 512 float4, 2 per thread
#pragma unroll
    for (int i = 0; i < 2; ++i) {
      int idx = i * 256 + tid;
      int r = idx >> 4, c4 = (idx & 15) * 4;
      float4 v = ((const float4*)ctrs)[(size_t)(c * 32 + r) * 16 + (idx & 15)];
      Ct[r * CT_STRIDE + c4 + 0] = (half_t)v.x;
      Ct[r * CT_STRIDE + c4 + 1] = (half_t)v.y;
      Ct[r * CT_STRIDE + c4 + 2] = (half_t)v.z;
      Ct[r * CT_STRIDE + c4 + 3] = (half_t)v.w;
    }
    // csq2: k = tid>>3, 8 lanes each sum 8 d's, shuffle-reduce
    {
      int k = tid >> 3, dg = (tid & 7) * 8;
      const float* cp = ctrs + (size_t)(c * 32 + k) * DIN + dg;
      float acc = 0.0f;
#pragma unroll
      for (int j = 0; j < 8; ++j) acc = fmaf(cp[j] * cp[j], s[dg + j], acc);
      acc += __shfl_xor(acc, 1);
      acc += __shfl_xor(acc, 2);
      acc += __shfl_xor(acc, 4);
      if ((tid & 7) == 0) csq2[c * 32 + k] = acc * LOG2E;
    }
  }
  __syncthreads();

  if (w < 2) {  // 2 Vswz frags per block: sl = part*2 + w
    int sl = part * 2 + w;
    f16x8 v;
#pragma unroll
    for (int j = 0; j < 8; ++j) v[j] = Vt[(l4 * 8 + j) * 36 + w * 16 + lm];
    *(f16x8*)(Vswz + ((c * 16 + sl) * 64 + l) * 8) = v;
  }
  if (part == 0) {  // Cswz: frag f = w; ct = f>>1, kt = f&1
    int ct = w >> 1, kt = w & 1;
    f16x8 v;
#pragma unroll
    for (int j = 0; j < 8; ++j)
      v[j] = Ct[(ct * 16 + lm) * CT_STRIDE + kt * 32 + l4 * 8 + j];
    *(f16x8*)(Cswz + ((c * 4 + w) * 64 + l) * 8) = v;
  }
}

// ---------------------------------------------------------------------------
// Fused kernel, ROUND 4: BARRIER-FREE single-pass.
// Evidence from r0-r3: total wave count (65536/32 = 2048 = 2 waves/SIMD) caps
// occupancy; every block-barrier variant lockstepped the CU's phases and lost
// to the barrier-free r0 structure despite doing MORE work. So: r0's memory
// structure (V/C straight from global, L1/L2-hot, ZERO LDS, ZERO barriers,
// free wave drift) + the verified math wins of r1-r3 (single-pass online
// softmax with defer-max = -16% MFMA and one full C/V pass removed;
// in-register permlane P-transpose = no P LDS round-trip, no bank conflicts).
// Per chunk: [C(c+1)/csq(c+1) prefetch] -> QK(c) -> [issue 8 V-frag loads]
// -> softmax(c) (V latency hides under it) -> PV(c) (setprio 1).
// Block = 128 rows x 1024 ctrs (4 waves x 32 rows), grid 512.
// scores = (2*cross - csq)*log2e  (x^2 term cancels in softmax).
// ---------------------------------------------------------------------------
__global__ __launch_bounds__(256, 2) void attn_kernel(
    const float* __restrict__ x, const float* __restrict__ s,
    const char* __restrict__ ws, float* __restrict__ out) {
  const f16x8* __restrict__ cbase = (const f16x8*)(ws + CSWZ_OFF);
  const f16x8* __restrict__ vbase = (const f16x8*)(ws + VSWZ_OFF);
  const float* __restrict__ csq2 = (const float*)(ws + CSQ_OFF);

  const int tid = threadIdx.x;
  const int w = tid >> 6, l = tid & 63, l4 = l >> 4, lm = l & 15;
  const int rowbase = blockIdx.x * 128 + w * 32;

  // ---- x*s fragments (MFMA B-operand in the swapped QK^T); rows = lm
  f16x8 A[2][2];
#pragma unroll
  for (int rt = 0; rt < 2; ++rt) {
#pragma unroll
    for (int kt = 0; kt < 2; ++kt) {
      int din = kt * 32 + l4 * 8;
      const float* src = x + (size_t)(rowbase + rt * 16 + lm) * DIN + din;
      f16x8 a;
#pragma unroll
      for (int j = 0; j < 8; ++j) a[j] = (half_t)(src[j] * s[din + j]);
      A[rt][kt] = a;
    }
  }

  // all-ones row-0 A-frag for the L (row-sum) MFMA
  f16x8 ones;
#pragma unroll
  for (int j = 0; j < 8; ++j) ones[j] = (lm == 0) ? (half_t)1.0f : (half_t)0.0f;

  f32x4 O[2][16];  // O^T: lane holds [dout = u*16 + l4*4 + reg][r = lm]
  f32x4 Lacc[2];
  float m[2] = {-1e30f, -1e30f};
#pragma unroll
  for (int rt = 0; rt < 2; ++rt) {
    Lacc[rt] = (f32x4){0.f, 0.f, 0.f, 0.f};
#pragma unroll
    for (int u = 0; u < 16; ++u) O[rt][u] = (f32x4){0.f, 0.f, 0.f, 0.f};
  }

  // ---- depth-1 prefetch of C-frags + csq
  f16x8 nb0 = cbase[0 * 64 + l], nb1 = cbase[1 * 64 + l];
  f16x8 nb2 = cbase[2 * 64 + l], nb3 = cbase[3 * 64 + l];
  f32x4 ncs0 = *(const f32x4*)(csq2 + l4 * 4);
  f32x4 ncs1 = *(const f32x4*)(csq2 + 16 + l4 * 4);

#pragma unroll 1
  for (int c = 0; c < 32; ++c) {
    f16x8 b0 = nb0, b1 = nb1, b2 = nb2, b3 = nb3;
    f32x4 cs0 = ncs0, cs1 = ncs1;
    int cn = (c < 31) ? c + 1 : 31;  // depth-1 prefetch (clamped)
    nb0 = cbase[(cn * 4 + 0) * 64 + l];
    nb1 = cbase[(cn * 4 + 1) * 64 + l];
    nb2 = cbase[(cn * 4 + 2) * 64 + l];
    nb3 = cbase[(cn * 4 + 3) * 64 + l];
    ncs0 = *(const f32x4*)(csq2 + cn * 32 + l4 * 4);
    ncs1 = *(const f32x4*)(csq2 + cn * 32 + 16 + l4 * 4);

    // ---- swapped QK^T: rows = centers (l4*4+j), cols = x-rows (lm)
    f32x4 t0[2], t1[2];
#pragma unroll
    for (int rt = 0; rt < 2; ++rt) {
      f32x4 a0 = {0.f, 0.f, 0.f, 0.f}, a1 = {0.f, 0.f, 0.f, 0.f};
      a0 = __builtin_amdgcn_mfma_f32_16x16x32_f16(b0, A[rt][0], a0, 0, 0, 0);
      a0 = __builtin_amdgcn_mfma_f32_16x16x32_f16(b1, A[rt][1], a0, 0, 0, 0);
      a1 = __builtin_amdgcn_mfma_f32_16x16x32_f16(b2, A[rt][0], a1, 0, 0, 0);
      a1 = __builtin_amdgcn_mfma_f32_16x16x32_f16(b3, A[rt][1], a1, 0, 0, 0);
      t0[rt] = a0;
      t1[rt] = a1;
    }

    // ---- issue first-half V-frag loads now; latency hides under softmax
    f16x8 vf[8];
#pragma unroll
    for (int u = 0; u < 8; ++u) vf[u] = vbase[(c * 16 + u) * 64 + l];

    // ---- softmax(c): online, defer-max, in-register P transpose
    f16x8 pb[2];
#pragma unroll
    for (int rt = 0; rt < 2; ++rt) {
      float v0[4], v1[4];
#pragma unroll
      for (int j = 0; j < 4; ++j) {
        v0[j] = fmaf(t0[rt][j], 2.0f * LOG2E, -cs0[j]);
        v1[j] = fmaf(t1[rt][j], 2.0f * LOG2E, -cs1[j]);
      }
      float pm = fmaxf(fmaxf(fmaxf(v0[0], v0[1]), fmaxf(v0[2], v0[3])),
                       fmaxf(fmaxf(v1[0], v1[1]), fmaxf(v1[2], v1[3])));
      pm = fmaxf(pm, __shfl_xor(pm, 16));
      pm = fmaxf(pm, __shfl_xor(pm, 32));

      if (__any(pm > m[rt] + RESCALE_THR)) {
        float mn = fmaxf(m[rt], pm);
        float f = __builtin_amdgcn_exp2f(m[rt] - mn);  // per-lane (row lm)
        m[rt] = mn;
        Lacc[rt] *= f;
#pragma unroll
        for (int u = 0; u < 16; ++u) O[rt][u] *= f;
      }

      unsigned wds[4];
#pragma unroll
      for (int h = 0; h < 2; ++h) {
        union { half_t h2[2]; unsigned u; } qa, qb;
        qa.h2[0] = (half_t)__builtin_amdgcn_exp2f(v0[2 * h] - m[rt]);
        qa.h2[1] = (half_t)__builtin_amdgcn_exp2f(v0[2 * h + 1] - m[rt]);
        qb.h2[0] = (half_t)__builtin_amdgcn_exp2f(v1[2 * h] - m[rt]);
        qb.h2[1] = (half_t)__builtin_amdgcn_exp2f(v1[2 * h + 1] - m[rt]);
        u32x2 sw1 = __builtin_amdgcn_permlane32_swap(qa.u, qb.u, false, false);
        u32x2 sw2 = __builtin_amdgcn_permlane16_swap(sw1.x, sw1.y, false, false);
        wds[h] = sw2.x;       // word h   : elements 2h,2h+1
        wds[h + 2] = sw2.y;   // word h+2 : elements 2h+4,2h+5
      }
      union { unsigned u[4]; f16x8 v; } pk;
      pk.u[0] = wds[0]; pk.u[1] = wds[1]; pk.u[2] = wds[2]; pk.u[3] = wds[3];
      pb[rt] = pk.v;
    }

    // ---- PV(c): O^T += V^T * P^T. First half from prefetched regs,
    // second half direct (compiler hoists as register budget allows).
    __builtin_amdgcn_s_setprio(1);
#pragma unroll
    for (int u = 0; u < 8; ++u) {
      O[0][u] = __builtin_amdgcn_mfma_f32_16x16x32_f16(vf[u], pb[0], O[0][u], 0, 0, 0);
      O[1][u] = __builtin_amdgcn_mfma_f32_16x16x32_f16(vf[u], pb[1], O[1][u], 0, 0, 0);
    }
#pragma unroll
    for (int u = 8; u < 16; ++u) {
      f16x8 vfl = vbase[(c * 16 + u) * 64 + l];
      O[0][u] = __builtin_amdgcn_mfma_f32_16x16x32_f16(vfl, pb[0], O[0][u], 0, 0, 0);
      O[1][u] = __builtin_amdgcn_mfma_f32_16x16x32_f16(vfl, pb[1], O[1][u], 0, 0, 0);
    }
    Lacc[0] = __builtin_amdgcn_mfma_f32_16x16x32_f16(ones, pb[0], Lacc[0], 0, 0, 0);
    Lacc[1] = __builtin_amdgcn_mfma_f32_16x16x32_f16(ones, pb[1], Lacc[1], 0, 0, 0);
    __builtin_amdgcn_s_setprio(0);
  }

  // ---- epilogue: L row-sum = D[0][r] of ones-MFMA: lane r (0..15), reg 0.
  // O^T layout -> 4 consecutive douts per lane: contiguous dwordx4 stores.
#pragma unroll
  for (int rt = 0; rt < 2; ++rt) {
    float lv = __shfl(Lacc[rt][0], lm);
    float inv = 1.0f / fmaxf(lv, 1e-30f);
    float* po = out + (size_t)(rowbase + rt * 16 + lm) * DOUT + l4 * 4;
#pragma unroll
    for (int u = 0; u < 16; ++u) {
      f32x4 ov = O[rt][u] * inv;
      *(f32x4*)(po + u * 16) = ov;
    }
  }
}

extern "C" void kernel_launch(void* const* d_in, const int* in_sizes, int n_in,
                              void* d_out, int out_size, void* d_ws, size_t ws_size,
                              hipStream_t stream) {
  const float* x = (const float*)d_in[0];
  const float* ctrs = (const float*)d_in[1];
  const float* values = (const float*)d_in[2];
  const float* s = (const float*)d_in[3];
  float* out = (float*)d_out;
  char* ws = (char*)d_ws;

  hipLaunchKernelGGL(precompute_kernel, dim3(256), dim3(256), 0, stream,
                     ctrs, values, s, ws);
  hipLaunchKernelGGL(attn_kernel, dim3(512), dim3(256), 0, stream,
                     x, s, ws, out);
}